// Round 3
// baseline (1223.627 us; speedup 1.0000x reference)
//
#include <hip/hip_runtime.h>

#define NB 16
#define HH 256
#define WW 256
#define NPIX (HH*WW)

typedef _Float16 f16;
typedef _Float16 f16x8 __attribute__((ext_vector_type(8)));
typedef float f32x4 __attribute__((ext_vector_type(4)));

// ---------------------------------------------------------------------------
// prepack: head weights -> f16.  wpA [64][32] (k=cin*9+tap, pad>=18),
// wpB [64][576] (k=tap*64+cin), wpC [96][576] (rows>=81 zero).
// ---------------------------------------------------------------------------
__global__ __launch_bounds__(256) void prepack_kernel(
    const float* __restrict__ wfa, const float* __restrict__ wfb,
    const float* __restrict__ wfc,
    f16* __restrict__ wpA, f16* __restrict__ wpB, f16* __restrict__ wpC)
{
    int i = blockIdx.x * 256 + threadIdx.x;
    if (i < 64 * 32) {
        int c = i >> 5, k = i & 31;
        wpA[i] = (f16)(k < 18 ? wfa[c * 18 + k] : 0.f);
    }
    if (i < 64 * 576) {
        int c = i / 576, k = i % 576;
        int tap = k >> 6, cin = k & 63;
        wpB[i] = (f16)wfb[(c * 64 + cin) * 9 + tap];
    }
    if (i < 96 * 576) {
        int c = i / 576, k = i % 576;
        int tap = k >> 6, cin = k & 63;
        wpC[i] = (f16)(c < 81 ? wfc[(c * 64 + cin) * 9 + tap] : 0.f);
    }
}

// ---------------------------------------------------------------------------
// mega kernel: whole network for one 16x16 output tile.
// LDS halves layout:
//   hb  [576][64] swz (branch hidden 24x24; later h1 [400][64])   36864
//   h2  [324][64] swz                                             20736
//   xg  [2][676]  f16 (26x26 input tiles, halo 5)                  1352
//   ft  [2][484]  f16 (feat 22x22, halo 3)                          968
//   wA1/wA2 [64][32] (branch conv1a packed)                    2048+2048
//   wAh [64][32]  (wfa packed)                                     2048
//   wpb [2][576]  (branch conv1b packed k=tap*64+cin)              1152
// then f32: xt24[576], bA1[64], bA2[64], bAh[64], bBh[64], bCh[96], bSc[2]
// ---------------------------------------------------------------------------
#define HB_OFF   0
#define H2_OFF   36864
#define XG_OFF   57600
#define FT_OFF   58952
#define WA1_OFF  59920
#define WA2_OFF  61968
#define WAH_OFF  64016
#define WPB_OFF  66064
#define HALVES_T 67216
#define NFLOATS  (576+64+64+64+64+96+2)

__global__ __launch_bounds__(512) void mega_kernel(
    const float* __restrict__ x, const float* __restrict__ gin,
    const float* __restrict__ w1a, const float* __restrict__ b1a,
    const float* __restrict__ w1b, const float* __restrict__ b1b,
    const float* __restrict__ w2a, const float* __restrict__ b2a,
    const float* __restrict__ w2b, const float* __restrict__ b2b,
    const f16* __restrict__ wpA, const f16* __restrict__ wpB,
    const f16* __restrict__ wpC,
    const float* __restrict__ bfa, const float* __restrict__ bfb,
    const float* __restrict__ bfc, float* __restrict__ out)
{
    extern __shared__ f16 sm[];
    f16* hb  = sm + HB_OFF;
    f16* h2  = sm + H2_OFF;
    f16* xg  = sm + XG_OFF;
    f16* ft  = sm + FT_OFF;
    f16* wA1 = sm + WA1_OFF;
    f16* wA2 = sm + WA2_OFF;
    f16* wAh = sm + WAH_OFF;
    f16* wpb = sm + WPB_OFF;
    float* fbse = (float*)(sm + HALVES_T);
    float* xt24 = fbse;          // 576
    float* bA1  = xt24 + 576;
    float* bA2  = bA1 + 64;
    float* bAh  = bA2 + 64;
    float* bBh  = bAh + 64;
    float* bCh  = bBh + 64;      // 96
    float* bSc  = bCh + 96;      // 2

    const int tid = threadIdx.x;
    const int wid = tid >> 6, lane = tid & 63;
    const int gq = lane >> 4, cl = lane & 15;
    const int x0 = blockIdx.x * 16, y0 = blockIdx.y * 16;
    const int b = blockIdx.z;

    // ---- P0: stage inputs + small weights ----
    const float* xb = x + (size_t)b * NPIX;
    const float* gb = gin + (size_t)b * NPIX;
    for (int t = tid; t < 1352; t += 512) {
        int p = t >= 676 ? t - 676 : t;
        int r = p / 26, c = p - 26 * r;
        int gy = y0 - 5 + r, gx = x0 - 5 + c;
        bool in = ((unsigned)gy < (unsigned)HH && (unsigned)gx < (unsigned)WW);
        float v = in ? (t >= 676 ? gb : xb)[gy * WW + gx] : 0.f;
        xg[t] = (f16)v;
        if (t < 676 && r >= 1 && r < 25 && c >= 1 && c < 25)
            xt24[(r - 1) * 24 + (c - 1)] = v;
    }
    for (int t = tid; t < 2048; t += 512) {
        int cc = t >> 5, k = t & 31;
        wA1[t] = (f16)(k < 9 ? w1a[cc * 9 + k] : 0.f);
        wA2[t] = (f16)(k < 9 ? w2a[cc * 9 + k] : 0.f);
        wAh[t] = wpA[t];
    }
    for (int t = tid; t < 1152; t += 512) {
        int br = t / 576, k = t - 576 * br;
        int tap = k >> 6, cin = k & 63;
        wpb[t] = (f16)((br ? w2b : w1b)[cin * 9 + tap]);
    }
    if (tid < 64) {
        bA1[tid] = b1a[tid]; bA2[tid] = b2a[tid];
        bAh[tid] = bfa[tid]; bBh[tid] = bfb[tid];
    } else if (tid >= 64 && tid < 160) {
        bCh[tid - 64] = (tid - 64) < 81 ? bfc[tid - 64] : 0.f;
    } else if (tid == 160) { bSc[0] = b1b[0]; bSc[1] = b2b[0]; }
    __syncthreads();

    // ---- branches: hidden (B1) then feat (B2), sequential over br ----
    #pragma unroll 1
    for (int br = 0; br < 2; br++) {
        const f16* wAb = br ? wA2 : wA1;
        const float* bAb = br ? bA2 : bA1;

        // B1: hidden = relu(conv1a(x|g)), 24x24 region, 64 ch -> hb (swz)
        {
            f16x8 bb[4];
            #pragma unroll
            for (int nt = 0; nt < 4; nt++)
                bb[nt] = *(const f16x8*)&wAb[(nt * 16 + cl) * 32 + gq * 8];
            for (int mt = wid; mt < 36; mt += 8) {
                int p = mt * 16 + cl;
                int py = p / 24, px = p - 24 * py;
                f16x8 a;
                #pragma unroll
                for (int j = 0; j < 8; j++) {
                    int k = gq * 8 + j;
                    float v = 0.f;
                    if (k < 9) {
                        int u = k / 3, vv = k - 3 * u;
                        v = (float)xg[br * 676 + (py + u) * 26 + px + vv];
                    }
                    a[j] = (f16)v;
                }
                f32x4 acc[4];
                #pragma unroll
                for (int nt = 0; nt < 4; nt++) {
                    f32x4 z = {0.f, 0.f, 0.f, 0.f};
                    acc[nt] = __builtin_amdgcn_mfma_f32_16x16x32_f16(a, bb[nt], z, 0, 0, 0);
                }
                #pragma unroll
                for (int nt = 0; nt < 4; nt++)
                    #pragma unroll
                    for (int reg = 0; reg < 4; reg++) {
                        int pd = mt * 16 + gq * 4 + reg;
                        int ch = nt * 16 + cl;
                        int pdy = pd / 24, pdx = pd - 24 * pdy;
                        int gy = y0 - 4 + pdy, gx = x0 - 4 + pdx;
                        float v = ((unsigned)gy < (unsigned)HH && (unsigned)gx < (unsigned)WW)
                            ? fmaxf(acc[nt][reg] + bAb[ch], 0.f) : 0.f;
                        hb[pd * 64 + (((ch >> 3) ^ (pd & 7)) << 3) + (ch & 7)] = (f16)v;
                    }
            }
        }
        __syncthreads();

        // B2: feat = conv1b(hidden)+bias, 22x22 region -> ft[br] (f16)
        {
            f32x4 accF[4];
            #pragma unroll
            for (int i = 0; i < 4; i++) accF[i] = (f32x4){0.f, 0.f, 0.f, 0.f};
            #pragma unroll
            for (int kk = 0; kk < 18; kk++) {
                int tap = kk >> 1, cb = (kk & 1) * 4;
                int u = tap / 3, v = tap - 3 * u;
                f16x8 bf = {(f16)0, (f16)0, (f16)0, (f16)0, (f16)0, (f16)0, (f16)0, (f16)0};
                if (cl == 0)
                    bf = *(const f16x8*)&wpb[br * 576 + kk * 32 + gq * 8];
                #pragma unroll
                for (int i = 0; i < 4; i++) {
                    int mt = wid + 8 * i;
                    if (mt < 31) {
                        int p = mt * 16 + cl; if (p > 483) p = 483;
                        int py = p / 22, px = p - 22 * py;
                        int hp = (py + u) * 24 + px + v;
                        f16x8 a = *(const f16x8*)&hb[hp * 64 + (((cb + gq) ^ (hp & 7)) << 3)];
                        accF[i] = __builtin_amdgcn_mfma_f32_16x16x32_f16(a, bf, accF[i], 0, 0, 0);
                    }
                }
            }
            if (cl == 0) {
                #pragma unroll
                for (int i = 0; i < 4; i++) {
                    int mt = wid + 8 * i;
                    if (mt < 31)
                        #pragma unroll
                        for (int reg = 0; reg < 4; reg++) {
                            int pd = mt * 16 + gq * 4 + reg;
                            if (pd < 484) {
                                int py = pd / 22, px = pd - 22 * py;
                                int gy = y0 - 3 + py, gx = x0 - 3 + px;
                                float v = ((unsigned)gy < (unsigned)HH && (unsigned)gx < (unsigned)WW)
                                    ? accF[i][reg] + bSc[br] : 0.f;
                                ft[br * 484 + pd] = (f16)v;
                            }
                        }
                }
            }
        }
        __syncthreads();
    }

    // ---- H1: h1 = relu(conv(ft, wfa)), 20x20 region -> hb (swz) ----
    {
        f16x8 bbh[4];
        #pragma unroll
        for (int nt = 0; nt < 4; nt++)
            bbh[nt] = *(const f16x8*)&wAh[(nt * 16 + cl) * 32 + gq * 8];
        for (int mt = wid; mt < 25; mt += 8) {
            int p = mt * 16 + cl;             // < 400
            int py = p / 20, px = p - 20 * py;
            f16x8 a;
            #pragma unroll
            for (int j = 0; j < 8; j++) {
                int k = gq * 8 + j;
                float v = 0.f;
                if (k < 18) {
                    int cin = k >= 9 ? 1 : 0;
                    int tap = k - 9 * cin;
                    int u = tap / 3, vv = tap - 3 * u;
                    v = (float)ft[cin * 484 + (py + u) * 22 + px + vv];
                }
                a[j] = (f16)v;
            }
            f32x4 acc[4];
            #pragma unroll
            for (int nt = 0; nt < 4; nt++) {
                f32x4 z = {0.f, 0.f, 0.f, 0.f};
                acc[nt] = __builtin_amdgcn_mfma_f32_16x16x32_f16(a, bbh[nt], z, 0, 0, 0);
            }
            #pragma unroll
            for (int nt = 0; nt < 4; nt++)
                #pragma unroll
                for (int reg = 0; reg < 4; reg++) {
                    int pd = mt * 16 + gq * 4 + reg;
                    int ch = nt * 16 + cl;
                    int pdy = pd / 20, pdx = pd - 20 * pdy;
                    int gy = y0 - 2 + pdy, gx = x0 - 2 + pdx;
                    float v = ((unsigned)gy < (unsigned)HH && (unsigned)gx < (unsigned)WW)
                        ? fmaxf(acc[nt][reg] + bAh[ch], 0.f) : 0.f;
                    hb[pd * 64 + (((ch >> 3) ^ (pd & 7)) << 3) + (ch & 7)] = (f16)v;
                }
        }
    }
    __syncthreads();

    // ---- H2: h2 = relu(conv(h1, wfb)), 18x18 region; B-frags from global ----
    {
        f32x4 accB[3][4];
        #pragma unroll
        for (int i = 0; i < 3; i++)
            #pragma unroll
            for (int nt = 0; nt < 4; nt++) accB[i][nt] = (f32x4){0.f, 0.f, 0.f, 0.f};
        #pragma unroll
        for (int kk = 0; kk < 18; kk++) {
            int tap = kk >> 1, cb = (kk & 1) * 4;
            int u = tap / 3, v = tap - 3 * u;
            f16x8 bf[4];
            #pragma unroll
            for (int nt = 0; nt < 4; nt++)
                bf[nt] = *(const f16x8*)&wpB[(nt * 16 + cl) * 576 + kk * 32 + gq * 8];
            #pragma unroll
            for (int i = 0; i < 3; i++) {
                int mt = wid + 8 * i;
                if (mt < 21) {
                    int p = mt * 16 + cl; if (p > 323) p = 323;
                    int py = p / 18, px = p - 18 * py;
                    int hp = (py + u) * 20 + px + v;
                    f16x8 a = *(const f16x8*)&hb[hp * 64 + (((cb + gq) ^ (hp & 7)) << 3)];
                    #pragma unroll
                    for (int nt = 0; nt < 4; nt++)
                        accB[i][nt] = __builtin_amdgcn_mfma_f32_16x16x32_f16(
                            a, bf[nt], accB[i][nt], 0, 0, 0);
                }
            }
        }
        #pragma unroll
        for (int i = 0; i < 3; i++) {
            int mt = wid + 8 * i;
            if (mt < 21)
                #pragma unroll
                for (int nt = 0; nt < 4; nt++)
                    #pragma unroll
                    for (int reg = 0; reg < 4; reg++) {
                        int pd = mt * 16 + gq * 4 + reg;
                        if (pd < 324) {
                            int ch = nt * 16 + cl;
                            int pdy = pd / 18, pdx = pd - 18 * pdy;
                            int gy = y0 - 1 + pdy, gx = x0 - 1 + pdx;
                            float v = ((unsigned)gy < (unsigned)HH && (unsigned)gx < (unsigned)WW)
                                ? fmaxf(accB[i][nt][reg] + bBh[ch], 0.f) : 0.f;
                            h2[pd * 64 + (((ch >> 3) ^ (pd & 7)) << 3) + (ch & 7)] = (f16)v;
                        }
                    }
        }
    }
    __syncthreads();

    // ---- H3: logits = conv(h2, wfc)+bfc, 16x16, 96 couts; B from global ----
    f32x4 accC[2][6];
    #pragma unroll
    for (int i = 0; i < 2; i++)
        #pragma unroll
        for (int nt = 0; nt < 6; nt++) accC[i][nt] = (f32x4){0.f, 0.f, 0.f, 0.f};
    #pragma unroll
    for (int kk = 0; kk < 18; kk++) {
        int tap = kk >> 1, cb = (kk & 1) * 4;
        int u = tap / 3, v = tap - 3 * u;
        f16x8 bf[6];
        #pragma unroll
        for (int nt = 0; nt < 6; nt++)
            bf[nt] = *(const f16x8*)&wpC[(nt * 16 + cl) * 576 + kk * 32 + gq * 8];
        #pragma unroll
        for (int i = 0; i < 2; i++) {
            int mt = wid * 2 + i;                 // pixel row = mt, col = cl
            int hp = (mt + u) * 18 + cl + v;
            f16x8 a = *(const f16x8*)&h2[hp * 64 + (((cb + gq) ^ (hp & 7)) << 3)];
            #pragma unroll
            for (int nt = 0; nt < 6; nt++)
                accC[i][nt] = __builtin_amdgcn_mfma_f32_16x16x32_f16(
                    a, bf[nt], accC[i][nt], 0, 0, 0);
        }
    }

    // ---- softmax over 81 taps + apply 9x9 patch ----
    #pragma unroll
    for (int i = 0; i < 2; i++) {
        int mt = wid * 2 + i;
        #pragma unroll
        for (int reg = 0; reg < 4; reg++) {
            int py = mt, px = gq * 4 + reg;
            float val[6];
            #pragma unroll
            for (int nt = 0; nt < 6; nt++)
                val[nt] = accC[i][nt][reg] + bCh[nt * 16 + cl];
            if (cl != 0) val[5] = -1e30f;      // couts 81..95 invalid
            float m = val[0];
            #pragma unroll
            for (int nt = 1; nt < 6; nt++) m = fmaxf(m, val[nt]);
            #pragma unroll
            for (int d = 1; d < 16; d <<= 1) m = fmaxf(m, __shfl_xor(m, d));
            float s = 0.f, o = 0.f;
            #pragma unroll
            for (int nt = 0; nt < 6; nt++) {
                int c = nt * 16 + cl;
                int cs = c > 80 ? 80 : c;
                float e = __expf(val[nt] - m);
                s += e;
                int u9 = cs / 9, v9 = cs - 9 * u9;
                o += e * xt24[(py + u9) * 24 + px + v9];
            }
            #pragma unroll
            for (int d = 1; d < 16; d <<= 1) {
                s += __shfl_xor(s, d);
                o += __shfl_xor(o, d);
            }
            if (cl == 0)
                out[(size_t)b * NPIX + (y0 + py) * WW + (x0 + px)] = o / s;
        }
    }
}

// ---------------------------------------------------------------------------
extern "C" void kernel_launch(void* const* d_in, const int* in_sizes, int n_in,
                              void* d_out, int out_size, void* d_ws, size_t ws_size,
                              hipStream_t stream)
{
    const float* x   = (const float*)d_in[0];
    const float* g   = (const float*)d_in[1];
    const float* w1a = (const float*)d_in[2];  const float* b1a = (const float*)d_in[3];
    const float* w1b = (const float*)d_in[4];  const float* b1b = (const float*)d_in[5];
    const float* w2a = (const float*)d_in[6];  const float* b2a = (const float*)d_in[7];
    const float* w2b = (const float*)d_in[8];  const float* b2b = (const float*)d_in[9];
    const float* wfa = (const float*)d_in[10]; const float* bfa = (const float*)d_in[11];
    const float* wfb = (const float*)d_in[12]; const float* bfb = (const float*)d_in[13];
    const float* wfc = (const float*)d_in[14]; const float* bfc = (const float*)d_in[15];
    float* out = (float*)d_out;

    f16* wpA = (f16*)d_ws;                 // 2048
    f16* wpB = wpA + 2048;                 // 36864
    f16* wpC = wpB + 36864;                // 55296

    prepack_kernel<<<dim3(216), 256, 0, stream>>>(wfa, wfb, wfc, wpA, wpB, wpC);

    size_t sh = (size_t)HALVES_T * 2 + (size_t)NFLOATS * 4;   // 138152 B
    mega_kernel<<<dim3(16, 16, NB), 512, sh, stream>>>(
        x, g, w1a, b1a, w1b, b1b, w2a, b2a, w2b, b2b,
        wpA, wpB, wpC, bfa, bfb, bfc, out);
}

// Round 4
// 690.791 us; speedup vs baseline: 1.7713x; 1.7713x over previous
//
#include <hip/hip_runtime.h>

#define NB 16
#define HH 256
#define WW 256
#define NPIX (HH*WW)

typedef _Float16 f16;
typedef _Float16 f16x8 __attribute__((ext_vector_type(8)));
typedef float f32x4 __attribute__((ext_vector_type(4)));

// slotted+swizzled f16 LDS tile [P][64]: slot (16B, 8 f16) index XOR'd with p&7
__device__ __forceinline__ int swzoff(int p, int c) {
    return p * 64 + ((((c >> 3) ^ (p & 7)) << 3) | (c & 7));
}

// ---------------------------------------------------------------------------
// prepack: all weights -> f16 packed, k-orderings chosen per consumer.
// pA1/pA2 [64][32] k=tap(9,pad32); pWa [64][32] k=cin*9+tap(18,pad32);
// pB1/pB2 [16][576] row0=w{1,2}b k=tap*64+cin, rows1-15 zero;
// pWb [64][576] k=tap*64+cin; pWc [96][576] rows81-95 zero.
// ---------------------------------------------------------------------------
__global__ __launch_bounds__(256) void prepack_kernel(
    const float* __restrict__ w1a, const float* __restrict__ w2a,
    const float* __restrict__ w1b, const float* __restrict__ w2b,
    const float* __restrict__ wfa, const float* __restrict__ wfb,
    const float* __restrict__ wfc,
    f16* __restrict__ pA1, f16* __restrict__ pA2, f16* __restrict__ pWa,
    f16* __restrict__ pB1, f16* __restrict__ pB2,
    f16* __restrict__ pWb, f16* __restrict__ pWc)
{
    int i = blockIdx.x * 256 + threadIdx.x;
    if (i < 2048) {
        int c = i >> 5, k = i & 31;
        pA1[i] = (f16)(k < 9 ? w1a[c * 9 + k] : 0.f);
        pA2[i] = (f16)(k < 9 ? w2a[c * 9 + k] : 0.f);
        pWa[i] = (f16)(k < 18 ? wfa[c * 18 + k] : 0.f);
    }
    if (i < 9216) {
        int r = i / 576, k = i % 576;
        int tap = k >> 6, cin = k & 63;
        pB1[i] = (f16)(r == 0 ? w1b[cin * 9 + tap] : 0.f);
        pB2[i] = (f16)(r == 0 ? w2b[cin * 9 + tap] : 0.f);
    }
    if (i < 36864) {
        int c = i / 576, k = i % 576;
        int tap = k >> 6, cin = k & 63;
        pWb[i] = (f16)wfb[(c * 64 + cin) * 9 + tap];
    }
    if (i < 55296) {
        int r = i / 576, k = i % 576;
        int tap = k >> 6, cin = k & 63;
        pWc[i] = (f16)(r < 81 ? wfc[(r * 64 + cin) * 9 + tap] : 0.f);
    }
}

// ---------------------------------------------------------------------------
// K1: branch -> feat.  blockIdx.z = b*2+br.  hidden 18x18x64 in LDS (swz),
// conv1a via MFMA (K=9 pad 32), conv1b via MFMA (N=16, row0 valid).
// ---------------------------------------------------------------------------
__global__ __launch_bounds__(256, 3) void k1_branch(
    const float* __restrict__ x, const float* __restrict__ g,
    const float* __restrict__ b1a, const float* __restrict__ b2a,
    const float* __restrict__ b1b, const float* __restrict__ b2b,
    const f16* __restrict__ pA1, const f16* __restrict__ pA2,
    const f16* __restrict__ pB1, const f16* __restrict__ pB2,
    float* __restrict__ feat)
{
    __shared__ f16 xt[400];       // 20x20 input tile
    __shared__ f16 hid[20736];    // [324][64] swz
    __shared__ float bA[64];

    const int tid = threadIdx.x;
    const int wid = tid >> 6, lane = tid & 63;
    const int gq = lane >> 4, cl = lane & 15;
    const int x0 = blockIdx.x * 16, y0 = blockIdx.y * 16;
    const int b = blockIdx.z >> 1, br = blockIdx.z & 1;

    const float* in = (br ? g : x) + (size_t)b * NPIX;
    const f16* pA = br ? pA2 : pA1;
    const f16* pB = br ? pB2 : pB1;
    const float bscal = (br ? b2b : b1b)[0];

    for (int t = tid; t < 400; t += 256) {
        int r = t / 20, c = t % 20;
        int gy = y0 - 2 + r, gx = x0 - 2 + c;
        xt[t] = (f16)(((unsigned)gy < (unsigned)HH && (unsigned)gx < (unsigned)WW)
                          ? in[gy * WW + gx] : 0.f);
    }
    if (tid < 64) bA[tid] = (br ? b2a : b1a)[tid];

    // A-frags for conv1a (weights, rows=couts), loaded once from global
    f16x8 afA[4];
    #pragma unroll
    for (int mt = 0; mt < 4; mt++)
        afA[mt] = *(const f16x8*)&pA[(mt * 16 + cl) * 32 + gq * 8];
    __syncthreads();

    // conv1a: hidden 18x18 region
    for (int nt = wid; nt < 21; nt += 4) {
        int p = nt * 16 + cl;
        int pc = p > 323 ? 323 : p;
        int py = pc / 18, px = pc - 18 * py;
        f16x8 bf = {};
        #pragma unroll
        for (int j = 0; j < 8; j++) {
            int k = gq * 8 + j;
            if (k < 9) {
                int u = k / 3, v = k - 3 * u;
                bf[j] = xt[(py + u) * 20 + px + v];
            }
        }
        int gy = y0 - 1 + py, gx = x0 - 1 + px;
        bool ok = (p < 324) &&
                  ((unsigned)gy < (unsigned)HH && (unsigned)gx < (unsigned)WW);
        #pragma unroll
        for (int mt = 0; mt < 4; mt++) {
            f32x4 z = {0.f, 0.f, 0.f, 0.f};
            f32x4 acc = __builtin_amdgcn_mfma_f32_16x16x32_f16(afA[mt], bf, z, 0, 0, 0);
            if (p < 324) {
                int c0 = mt * 16 + gq * 4;
                union { f16 h[4]; uint2 u2; } pk;
                #pragma unroll
                for (int r = 0; r < 4; r++)
                    pk.h[r] = (f16)(ok ? fmaxf(acc[r] + bA[c0 + r], 0.f) : 0.f);
                *(uint2*)&hid[swzoff(p, c0)] = pk.u2;
            }
        }
    }
    __syncthreads();

    // conv1b: feat 16x16, N-waste (row0 only). kk = tap*2 + cin-half.
    f32x4 accF[4];
    #pragma unroll
    for (int i = 0; i < 4; i++) accF[i] = (f32x4){0.f, 0.f, 0.f, 0.f};
    #pragma unroll 2
    for (int kk = 0; kk < 18; kk++) {
        int tap = kk >> 1;
        int u = tap / 3, v = tap - 3 * u;
        int c0 = (kk & 1) * 32 + gq * 8;
        f16x8 af = *(const f16x8*)&pB[cl * 576 + kk * 32 + gq * 8];
        #pragma unroll
        for (int i = 0; i < 4; i++) {
            int nt = wid * 4 + i;
            int hp = (nt + u) * 18 + cl + v;
            f16x8 bf = *(const f16x8*)&hid[swzoff(hp, c0)];
            accF[i] = __builtin_amdgcn_mfma_f32_16x16x32_f16(af, bf, accF[i], 0, 0, 0);
        }
    }
    if (gq == 0) {
        #pragma unroll
        for (int i = 0; i < 4; i++) {
            int nt = wid * 4 + i;   // row of tile; pixel col = cl; cout row 0 = reg 0
            feat[((size_t)(b * 2 + br)) * NPIX + (y0 + nt) * WW + x0 + cl] =
                accF[i][0] + bscal;
        }
    }
}

// ---------------------------------------------------------------------------
// K2: feat -> h1 (LDS, 18x18) -> h2 (HBM f16 [ci][pix][64]).
// ---------------------------------------------------------------------------
__global__ __launch_bounds__(256, 3) void k2_wfab(
    const float* __restrict__ feat, const f16* __restrict__ pWa,
    const f16* __restrict__ pWb, const float* __restrict__ bfa,
    const float* __restrict__ bfb, f16* __restrict__ h2g, int b0)
{
    __shared__ f16 ftt[800];      // [2][400] feat tile 20x20
    __shared__ f16 hid[20736];    // h1 [324][64] swz
    __shared__ float bA[64];
    __shared__ float bB[64];

    const int tid = threadIdx.x;
    const int wid = tid >> 6, lane = tid & 63;
    const int gq = lane >> 4, cl = lane & 15;
    const int x0 = blockIdx.x * 16, y0 = blockIdx.y * 16;
    const int ci = blockIdx.z, b = b0 + ci;

    for (int t = tid; t < 800; t += 256) {
        int cin = t / 400, p = t - 400 * cin;
        int r = p / 20, c = p - 20 * r;
        int gy = y0 - 2 + r, gx = x0 - 2 + c;
        ftt[t] = (f16)(((unsigned)gy < (unsigned)HH && (unsigned)gx < (unsigned)WW)
                           ? feat[((size_t)(b * 2 + cin)) * NPIX + gy * WW + gx] : 0.f);
    }
    if (tid < 64) { bA[tid] = bfa[tid]; bB[tid] = bfb[tid]; }

    f16x8 afA[4];
    #pragma unroll
    for (int mt = 0; mt < 4; mt++)
        afA[mt] = *(const f16x8*)&pWa[(mt * 16 + cl) * 32 + gq * 8];
    __syncthreads();

    // wfa: h1 18x18, k = cin*9+tap (18, pad 32)
    for (int nt = wid; nt < 21; nt += 4) {
        int p = nt * 16 + cl;
        int pc = p > 323 ? 323 : p;
        int py = pc / 18, px = pc - 18 * py;
        f16x8 bf = {};
        #pragma unroll
        for (int j = 0; j < 8; j++) {
            int k = gq * 8 + j;
            if (k < 18) {
                int cin = k >= 9 ? 1 : 0;
                int tap = k - 9 * cin;
                int u = tap / 3, v = tap - 3 * u;
                bf[j] = ftt[cin * 400 + (py + u) * 20 + px + v];
            }
        }
        int gy = y0 - 1 + py, gx = x0 - 1 + px;
        bool ok = (p < 324) &&
                  ((unsigned)gy < (unsigned)HH && (unsigned)gx < (unsigned)WW);
        #pragma unroll
        for (int mt = 0; mt < 4; mt++) {
            f32x4 z = {0.f, 0.f, 0.f, 0.f};
            f32x4 acc = __builtin_amdgcn_mfma_f32_16x16x32_f16(afA[mt], bf, z, 0, 0, 0);
            if (p < 324) {
                int c0 = mt * 16 + gq * 4;
                union { f16 h[4]; uint2 u2; } pk;
                #pragma unroll
                for (int r = 0; r < 4; r++)
                    pk.h[r] = (f16)(ok ? fmaxf(acc[r] + bA[c0 + r], 0.f) : 0.f);
                *(uint2*)&hid[swzoff(p, c0)] = pk.u2;
            }
        }
    }
    __syncthreads();

    // wfb: h2 16x16 x 64
    f32x4 acc[4][4];
    #pragma unroll
    for (int i = 0; i < 4; i++)
        #pragma unroll
        for (int mt = 0; mt < 4; mt++) acc[i][mt] = (f32x4){0.f, 0.f, 0.f, 0.f};
    #pragma unroll 2
    for (int kk = 0; kk < 18; kk++) {
        int tap = kk >> 1;
        int u = tap / 3, v = tap - 3 * u;
        int c0 = (kk & 1) * 32 + gq * 8;
        f16x8 af[4];
        #pragma unroll
        for (int mt = 0; mt < 4; mt++)
            af[mt] = *(const f16x8*)&pWb[(mt * 16 + cl) * 576 + kk * 32 + gq * 8];
        #pragma unroll
        for (int i = 0; i < 4; i++) {
            int nt = wid * 4 + i;
            int hp = (nt + u) * 18 + cl + v;
            f16x8 bf = *(const f16x8*)&hid[swzoff(hp, c0)];
            #pragma unroll
            for (int mt = 0; mt < 4; mt++)
                acc[i][mt] = __builtin_amdgcn_mfma_f32_16x16x32_f16(af[mt], bf, acc[i][mt], 0, 0, 0);
        }
    }
    #pragma unroll
    for (int i = 0; i < 4; i++) {
        int nt = wid * 4 + i;                       // tile row; pixel col = cl
        size_t pb = ((size_t)ci * NPIX + (size_t)((y0 + nt) * WW + x0 + cl)) * 64;
        #pragma unroll
        for (int mt = 0; mt < 4; mt++) {
            int c0 = mt * 16 + gq * 4;
            union { f16 h[4]; uint2 u2; } pk;
            #pragma unroll
            for (int r = 0; r < 4; r++)
                pk.h[r] = (f16)fmaxf(acc[i][mt][r] + bB[c0 + r], 0.f);
            *(uint2*)&h2g[pb + c0] = pk.u2;
        }
    }
}

// ---------------------------------------------------------------------------
// K3: h2 -> logits(96) -> softmax(81) -> patch apply -> out.
// ---------------------------------------------------------------------------
__global__ __launch_bounds__(256, 3) void k3_wfc_apply(
    const f16* __restrict__ h2g, const f16* __restrict__ pWc,
    const float* __restrict__ bfc, const float* __restrict__ x,
    float* __restrict__ out, int b0)
{
    __shared__ f16 h2t[20736];    // [324][64] swz
    __shared__ float xt24[576];   // 24x24
    __shared__ float bC[96];

    const int tid = threadIdx.x;
    const int wid = tid >> 6, lane = tid & 63;
    const int gq = lane >> 4, cl = lane & 15;
    const int x0 = blockIdx.x * 16, y0 = blockIdx.y * 16;
    const int ci = blockIdx.z, b = b0 + ci;

    for (int t = tid; t < 2592; t += 256) {
        int p = t >> 3, grp = t & 7;
        int py = p / 18, px = p - 18 * py;
        int gy = y0 - 1 + py, gx = x0 - 1 + px;
        f16x8 v = {};
        if ((unsigned)gy < (unsigned)HH && (unsigned)gx < (unsigned)WW)
            v = *(const f16x8*)&h2g[((size_t)ci * NPIX + (size_t)(gy * WW + gx)) * 64 + grp * 8];
        *(f16x8*)&h2t[swzoff(p, grp * 8)] = v;
    }
    const float* xb = x + (size_t)b * NPIX;
    for (int t = tid; t < 576; t += 256) {
        int r = t / 24, c = t - 24 * r;
        int gy = y0 - 4 + r, gx = x0 - 4 + c;
        xt24[t] = ((unsigned)gy < (unsigned)HH && (unsigned)gx < (unsigned)WW)
                      ? xb[gy * WW + gx] : 0.f;
    }
    if (tid < 96) bC[tid] = tid < 81 ? bfc[tid] : 0.f;
    __syncthreads();

    f32x4 acc[4][6];
    #pragma unroll
    for (int i = 0; i < 4; i++)
        #pragma unroll
        for (int mt = 0; mt < 6; mt++) acc[i][mt] = (f32x4){0.f, 0.f, 0.f, 0.f};
    #pragma unroll 2
    for (int kk = 0; kk < 18; kk++) {
        int tap = kk >> 1;
        int u = tap / 3, v = tap - 3 * u;
        int c0 = (kk & 1) * 32 + gq * 8;
        f16x8 af[6];
        #pragma unroll
        for (int mt = 0; mt < 6; mt++)
            af[mt] = *(const f16x8*)&pWc[(mt * 16 + cl) * 576 + kk * 32 + gq * 8];
        #pragma unroll
        for (int i = 0; i < 4; i++) {
            int nt = wid * 4 + i;
            int hp = (nt + u) * 18 + cl + v;
            f16x8 bf = *(const f16x8*)&h2t[swzoff(hp, c0)];
            #pragma unroll
            for (int mt = 0; mt < 6; mt++)
                acc[i][mt] = __builtin_amdgcn_mfma_f32_16x16x32_f16(af[mt], bf, acc[i][mt], 0, 0, 0);
        }
    }

    // softmax over taps (rows) for each pixel (col=cl); reduce across gq lanes
    #pragma unroll
    for (int i = 0; i < 4; i++) {
        int nt = wid * 4 + i;                       // pixel row; pixel col = cl
        float val[6][4];
        float m = -1e30f;
        #pragma unroll
        for (int mt = 0; mt < 6; mt++)
            #pragma unroll
            for (int r = 0; r < 4; r++) {
                int c = mt * 16 + gq * 4 + r;
                float vv = (c <= 80) ? acc[i][mt][r] + bC[c] : -1e30f;
                val[mt][r] = vv;
                m = fmaxf(m, vv);
            }
        m = fmaxf(m, __shfl_xor(m, 16));
        m = fmaxf(m, __shfl_xor(m, 32));
        float s = 0.f, o = 0.f;
        #pragma unroll
        for (int mt = 0; mt < 6; mt++)
            #pragma unroll
            for (int r = 0; r < 4; r++) {
                int c = mt * 16 + gq * 4 + r;
                if (c <= 80) {
                    float e = __expf(val[mt][r] - m);
                    int u9 = c / 9, v9 = c - 9 * u9;
                    s += e;
                    o += e * xt24[(nt + u9) * 24 + cl + v9];
                }
            }
        s += __shfl_xor(s, 16); s += __shfl_xor(s, 32);
        o += __shfl_xor(o, 16); o += __shfl_xor(o, 32);
        if (gq == 0)
            out[(size_t)b * NPIX + (y0 + nt) * WW + x0 + cl] = o / s;
    }
}

// ---------------------------------------------------------------------------
extern "C" void kernel_launch(void* const* d_in, const int* in_sizes, int n_in,
                              void* d_out, int out_size, void* d_ws, size_t ws_size,
                              hipStream_t stream)
{
    const float* x   = (const float*)d_in[0];
    const float* g   = (const float*)d_in[1];
    const float* w1a = (const float*)d_in[2];  const float* b1a = (const float*)d_in[3];
    const float* w1b = (const float*)d_in[4];  const float* b1b = (const float*)d_in[5];
    const float* w2a = (const float*)d_in[6];  const float* b2a = (const float*)d_in[7];
    const float* w2b = (const float*)d_in[8];  const float* b2b = (const float*)d_in[9];
    const float* wfa = (const float*)d_in[10]; const float* bfa = (const float*)d_in[11];
    const float* wfb = (const float*)d_in[12]; const float* bfb = (const float*)d_in[13];
    const float* wfc = (const float*)d_in[14]; const float* bfc = (const float*)d_in[15];
    float* out = (float*)d_out;

    // workspace: feat f32 | h2 chunk f16 | packed weights f16
    float* feat = (float*)d_ws;                       // 2,097,152 f32
    size_t featB = 2097152ull * 4;
    size_t pkB = 116736ull * 2;
    int nbc = 4;
    while (nbc > 1 && featB + (size_t)nbc * NPIX * 64 * 2 + pkB > ws_size) nbc >>= 1;

    f16* h2g = (f16*)((char*)d_ws + featB);
    f16* pk  = h2g + (size_t)nbc * NPIX * 64;
    f16* pA1 = pk;            // 2048
    f16* pA2 = pA1 + 2048;    // 2048
    f16* pWa = pA2 + 2048;    // 2048
    f16* pB1 = pWa + 2048;    // 9216
    f16* pB2 = pB1 + 9216;    // 9216
    f16* pWb = pB2 + 9216;    // 36864
    f16* pWc = pWb + 36864;   // 55296

    prepack_kernel<<<dim3(216), 256, 0, stream>>>(
        w1a, w2a, w1b, w2b, wfa, wfb, wfc, pA1, pA2, pWa, pB1, pB2, pWb, pWc);

    k1_branch<<<dim3(16, 16, 32), 256, 0, stream>>>(
        x, g, b1a, b2a, b1b, b2b, pA1, pA2, pB1, pB2, feat);

    for (int b0 = 0; b0 < NB; b0 += nbc) {
        int cn = (NB - b0) < nbc ? (NB - b0) : nbc;
        k2_wfab<<<dim3(16, 16, cn), 256, 0, stream>>>(
            feat, pWa, pWb, bfa, bfb, h2g, b0);
        k3_wfc_apply<<<dim3(16, 16, cn), 256, 0, stream>>>(
            h2g, pWc, bfc, x, out, b0);
    }
}